// Round 14
// baseline (315.611 us; speedup 1.0000x reference)
//
#include <hip/hip_runtime.h>

#define D 128
#define NG 128
#define EPB 2048      // edges per ascatter block
#define BSH 7         // 128-node buckets
#define BUCK 128
#define NB1MAX 1024   // max coarse buckets: N/128 (100k -> 782)

typedef unsigned short ushort_t;
typedef __bf16 bf16x8 __attribute__((ext_vector_type(8)));
typedef float floatx4 __attribute__((ext_vector_type(4)));

static __device__ __forceinline__ unsigned short f2bf(float f) {
    unsigned u = __float_as_uint(f);
    unsigned r = (u + 0x7fffu + ((u >> 16) & 1u)) >> 16;  // RNE
    return (unsigned short)r;
}
static __device__ __forceinline__ float bflo(unsigned v) { return __uint_as_float(v << 16); }
static __device__ __forceinline__ float bfhi(unsigned v) { return __uint_as_float(v & 0xffff0000u); }

// ---------- k_init (1 block): packW + 1/graph-counts (binary search) + out zero + cursor init ----------
__global__ __launch_bounds__(256) void k_init(const float* __restrict__ W, ushort_t* __restrict__ Wp,
                                              const int* __restrict__ batch, int N,
                                              float* __restrict__ cntinv, float* __restrict__ out,
                                              int* __restrict__ cursor, int nb1, int cap) {
    int tid = threadIdx.x;
    for (int t = tid; t < D * D; t += 256) {
        int c = t >> 7, k = t & 127;
        Wp[t] = f2bf(W[k * D + c]);
    }
    for (int i = tid; i < NG * D; i += 256) out[i] = 0.f;   // gather atomics accumulate into out
    for (int b = tid; b < nb1; b += 256) cursor[b] = b * cap;
    if (tid < NG) {
        int g = tid;
        int lo = 0, hi = N;
        while (lo < hi) { int mid = (lo + hi) >> 1; if (batch[mid] < g) lo = mid + 1; else hi = mid; }
        int a = lo;
        hi = N;
        while (lo < hi) { int mid = (lo + hi) >> 1; if (batch[mid] < g + 1) lo = mid + 1; else hi = mid; }
        int c = lo - a;
        cntinv[g] = 1.0f / (float)(c > 1 ? c : 1);
    }
}

// ---------- k_ascatter: in-LDS counting sort by 128-node bucket, coalesced copy-out ----------
__global__ __launch_bounds__(256) void k_ascatter(const int* __restrict__ src, const int* __restrict__ dst,
                                                  int E, int nb1, int* __restrict__ cursor,
                                                  int* __restrict__ ebuf) {
    __shared__ int sorted[EPB];         // 8 KB packed entries, bucket-ordered
    __shared__ int hist[NB1MAX];        // 4 KB
    __shared__ int bsum[256];           // 1 KB two-level scan
    __shared__ int lstart[NB1MAX + 1];  // 4 KB local run starts (exclusive)
    __shared__ int gofs[NB1MAX];        // 4 KB global base - lstart
    __shared__ int lcur[NB1MAX];        // 4 KB scatter cursors
    int tid = threadIdx.x;
    int base = blockIdx.x * EPB;
    int cntv = E - base; if (cntv > EPB) cntv = EPB;

    for (int b = tid; b < NB1MAX; b += 256) hist[b] = 0;
    __syncthreads();
    // phase 1: histogram (dst read #1, coalesced)
    for (int k = tid; k < cntv; k += 256) atomicAdd(&hist[dst[base + k] >> BSH], 1);
    __syncthreads();
    // phase 2: two-level exclusive scan over 1024 slots (4 slots/thread)
    int b4 = tid * 4;
    int h0 = hist[b4], h1 = hist[b4 + 1], h2 = hist[b4 + 2], h3 = hist[b4 + 3];
    int s0 = h0, s1 = s0 + h1, s2 = s1 + h2, s3 = s2 + h3;
    bsum[tid] = s3;
    __syncthreads();
    for (int off = 1; off < 256; off <<= 1) {
        int t = (tid >= off) ? bsum[tid - off] : 0;
        __syncthreads();
        bsum[tid] += t;
        __syncthreads();
    }
    int pre = bsum[tid] - s3;   // exclusive prefix of this thread's 4-slot group
    lstart[b4] = pre;
    lstart[b4 + 1] = pre + s0;
    lstart[b4 + 2] = pre + s1;
    lstart[b4 + 3] = pre + s2;
    lcur[b4] = pre;
    lcur[b4 + 1] = pre + s0;
    lcur[b4 + 2] = pre + s1;
    lcur[b4 + 3] = pre + s2;
#pragma unroll
    for (int q = 0; q < 4; ++q) {
        int b = b4 + q;
        if (b < nb1) {
            int v = hist[b];
            int g = v ? atomicAdd(&cursor[b], v) : 0;
            gofs[b] = g - lstart[b];
        }
    }
    if (tid == 0) lstart[nb1] = cntv;
    __syncthreads();
    // phase 3: LDS scatter (dst read #2 + src read, both L2-hot coalesced)
    for (int k = tid; k < cntv; k += 256) {
        int dv = dst[base + k];
        int sv = src[base + k];
        int pos = atomicAdd(&lcur[dv >> BSH], 1);
        sorted[pos] = sv | ((dv & (BUCK - 1)) << 24);
    }
    __syncthreads();
    // phase 4: coalesced copy-out; bucket via LDS binary search on lstart
    for (int k = tid; k < cntv; k += 256) {
        int lo = 0, hi = nb1 - 1;
        while (lo < hi) {
            int mid = (lo + hi + 1) >> 1;
            if (lstart[mid] <= k) lo = mid; else hi = mid - 1;
        }
        ebuf[gofs[lo] + k] = sorted[k];
    }
}

// ---------- k_bucket: per-128-node-bucket fine sort -> rs, deg, csr (LDS atomics only) ----------
__global__ __launch_bounds__(256) void k_bucket(const int* __restrict__ ebuf, const int* __restrict__ cursor,
                                                int cap, int nb1, int N,
                                                int* __restrict__ rs, int* __restrict__ deg,
                                                int* __restrict__ csr) {
    __shared__ int hist[256];     // slots 128..255 stay 0 (scan padding)
    __shared__ int sc[256];
    __shared__ int curs[BUCK];
    int tid = threadIdx.x;
    int b = blockIdx.x;
    int s = b * cap;
    int e = cursor[b];                  // after ascatter: s + bucket edge count
    int n0 = b << BSH;

    hist[tid] = 0;
    __syncthreads();
    for (int i = s + tid; i < e; i += 256) atomicAdd(&hist[(unsigned)ebuf[i] >> 24], 1);
    __syncthreads();
    int v = hist[tid];
    sc[tid] = v;
    __syncthreads();
    for (int off = 1; off < 256; off <<= 1) {
        int t = (tid >= off) ? sc[tid - off] : 0;
        __syncthreads();
        sc[tid] += t;
        __syncthreads();
    }
    int excl = sc[tid] - v;
    if (tid < BUCK) {
        int node = n0 + tid;
        if (node < N) {
            rs[node] = s + excl;
            deg[node] = v;
        }
        curs[tid] = s + excl;
    }
    __syncthreads();
    for (int i = s + tid; i < e; i += 256) {
        int p = ebuf[i];
        int pos = atomicAdd(&curs[(unsigned)p >> 24], 1);
        csr[pos] = p & 0x00FFFFFF;
    }
}

// ---------- MFMA GEMM: h[r][c] = bf16( dinv[r] * sum_k x[r][k]*W[k][c] ) ----------
__global__ __launch_bounds__(256) void k_gemm(const float* __restrict__ x, const ushort_t* __restrict__ Wp,
                                              const int* __restrict__ deg, ushort_t* __restrict__ h, int N) {
    __shared__ ushort_t hs[64][130];
    const int tid = threadIdx.x;
    const int w = tid >> 6;
    const int lane = tid & 63;
    const int q = lane >> 4;
    const int m = lane & 15;
    const int row0 = blockIdx.x * 64;
    const int arow = row0 + w * 16 + m;

    floatx4 acc[8];
#pragma unroll
    for (int nt = 0; nt < 8; ++nt) acc[nt] = (floatx4){0.f, 0.f, 0.f, 0.f};

    const bool rowok = (arow < N);
    const float* xrow = x + (size_t)arow * D;

#pragma unroll
    for (int kb = 0; kb < 4; ++kb) {
        union { bf16x8 v; ushort_t u[8]; } af;
        if (rowok) {
            float4 v0 = *(const float4*)&xrow[kb * 32 + q * 8];
            float4 v1 = *(const float4*)&xrow[kb * 32 + q * 8 + 4];
            af.u[0] = f2bf(v0.x); af.u[1] = f2bf(v0.y); af.u[2] = f2bf(v0.z); af.u[3] = f2bf(v0.w);
            af.u[4] = f2bf(v1.x); af.u[5] = f2bf(v1.y); af.u[6] = f2bf(v1.z); af.u[7] = f2bf(v1.w);
        } else {
#pragma unroll
            for (int j = 0; j < 8; ++j) af.u[j] = 0;
        }
#pragma unroll
        for (int nt = 0; nt < 8; ++nt) {
            int c = nt * 16 + m;
            const bf16x8 bf = *(const bf16x8*)(Wp + (size_t)c * D + kb * 32 + q * 8);
            acc[nt] = __builtin_amdgcn_mfma_f32_16x16x32_bf16(af.v, bf, acc[nt], 0, 0, 0);
        }
    }

    float di[4];
#pragma unroll
    for (int r = 0; r < 4; ++r) {
        int row = row0 + w * 16 + q * 4 + r;
        di[r] = (row < N) ? rsqrtf((float)(deg[row] + 1)) : 0.f;
    }
#pragma unroll
    for (int nt = 0; nt < 8; ++nt) {
        int c = nt * 16 + m;
#pragma unroll
        for (int r = 0; r < 4; ++r) {
            hs[w * 16 + q * 4 + r][c] = f2bf(acc[nt][r] * di[r]);
        }
    }
    __syncthreads();
#pragma unroll
    for (int it = 0; it < 8; ++it) {
        int f = it * 256 + tid;
        int r = f >> 5;
        int cq = f & 31;
        int row = row0 + r;
        if (row < N) {
            const ushort_t* p = &hs[r][cq * 4];
            uint2 vv;
            vv.x = (unsigned)p[0] | ((unsigned)p[1] << 16);
            vv.y = (unsigned)p[2] | ((unsigned)p[3] << 16);
            *(uint2*)&h[(size_t)row * D + cq * 4] = vv;
        }
    }
}

// ---------- gather: one wave/node, half-wave split, flush scaled by 1/cnt into out (unchanged) ----------
__global__ __launch_bounds__(256) void k_gather(const ushort_t* __restrict__ h, const int* __restrict__ rs,
                                                const int* __restrict__ deg, const int* __restrict__ csr,
                                                const int* __restrict__ batch, const float* __restrict__ b,
                                                const float* __restrict__ pa, const float* __restrict__ cntinv,
                                                float* __restrict__ out, int N) {
    __shared__ float rows[4][128];
    __shared__ int gids[4];
    const int wave = threadIdx.x >> 6;
    const int lane = threadIdx.x & 63;
    const int half = lane >> 5;        // half-wave: 0 -> even edges, 1 -> odd edges
    const int fl = lane & 31;          // feature lane: feats fl*4 .. fl*4+3
    const int node = blockIdx.x * 4 + wave;
    const int nodeC = (node < N) ? node : (N - 1);
    const bool valid = (node < N);

    float a0 = 0.f, a1 = 0.f, a2 = 0.f, a3 = 0.f;

    int start = rs[nodeC];
    int len = valid ? deg[nodeC] : 0;
    for (int o = 0; o < len; o += 64) {
        int m = len - o;
        if (m > 64) m = 64;
        int idx = (o + lane < len) ? csr[start + o + lane] : 0;
        int j = 0;
        for (; j + 8 <= m; j += 8) {     // 8 edges per group, 4 per half (4 loads in flight)
            int i0 = __shfl(idx, j + half);
            int i1 = __shfl(idx, j + 2 + half);
            int i2 = __shfl(idx, j + 4 + half);
            int i3 = __shfl(idx, j + 6 + half);
            uint2 v0 = *(const uint2*)&h[(size_t)i0 * D + fl * 4];
            uint2 v1 = *(const uint2*)&h[(size_t)i1 * D + fl * 4];
            uint2 v2 = *(const uint2*)&h[(size_t)i2 * D + fl * 4];
            uint2 v3 = *(const uint2*)&h[(size_t)i3 * D + fl * 4];
            a0 += bflo(v0.x); a1 += bfhi(v0.x); a2 += bflo(v0.y); a3 += bfhi(v0.y);
            a0 += bflo(v1.x); a1 += bfhi(v1.x); a2 += bflo(v1.y); a3 += bfhi(v1.y);
            a0 += bflo(v2.x); a1 += bfhi(v2.x); a2 += bflo(v2.y); a3 += bfhi(v2.y);
            a0 += bflo(v3.x); a1 += bfhi(v3.x); a2 += bflo(v3.y); a3 += bfhi(v3.y);
        }
        for (; j + 2 <= m; j += 2) {     // 2 edges, 1 per half
            int i0 = __shfl(idx, j + half);
            uint2 v0 = *(const uint2*)&h[(size_t)i0 * D + fl * 4];
            a0 += bflo(v0.x); a1 += bfhi(v0.x); a2 += bflo(v0.y); a3 += bfhi(v0.y);
        }
        if (j < m) {                     // odd tail: half 0 only (correct after combine)
            int i0 = __shfl(idx, j);
            if (half == 0) {
                uint2 v0 = *(const uint2*)&h[(size_t)i0 * D + fl * 4];
                a0 += bflo(v0.x); a1 += bfhi(v0.x); a2 += bflo(v0.y); a3 += bfhi(v0.y);
            }
        }
    }

    // combine halves -> both halves hold full neighbor sums
    a0 += __shfl_xor(a0, 32);
    a1 += __shfl_xor(a1, 32);
    a2 += __shfl_xor(a2, 32);
    a3 += __shfl_xor(a3, 32);

    // self-loop term (after combine: added exactly once per half)
    uint2 sv = *(const uint2*)&h[(size_t)nodeC * D + fl * 4];
    a0 += bflo(sv.x); a1 += bfhi(sv.x); a2 += bflo(sv.y); a3 += bfhi(sv.y);

    float dinv = rsqrtf((float)(len + 1));
    float4 bb = *(const float4*)&b[fl * 4];
    float4 aa = *(const float4*)&pa[fl * 4];
    float v0 = a0 * dinv + bb.x;
    float v1 = a1 * dinv + bb.y;
    float v2 = a2 * dinv + bb.z;
    float v3 = a3 * dinv + bb.w;
    v0 = v0 > 0.f ? v0 : aa.x * v0;
    v1 = v1 > 0.f ? v1 : aa.y * v1;
    v2 = v2 > 0.f ? v2 : aa.z * v2;
    v3 = v3 > 0.f ? v3 : aa.w * v3;
    float ss = v0 * v0 + v1 * v1 + v2 * v2 + v3 * v3;
#pragma unroll
    for (int o = 16; o > 0; o >>= 1) ss += __shfl_xor(ss, o);   // within each half-wave
    float inv = valid ? (1.0f / fmaxf(sqrtf(ss), 1e-12f)) : 0.f;

    if (half == 0) {
        *(float4*)&rows[wave][fl * 4] = make_float4(v0 * inv, v1 * inv, v2 * inv, v3 * inv);
        if (fl == 0) gids[wave] = batch[nodeC];
    }
    __syncthreads();

    // run-merge flush, scaled by 1/cnt(graph): atomics accumulate the final mean directly in out
    if (threadIdx.x < 128) {
        int f = threadIdx.x;
        float acc = rows[0][f];
        int g = gids[0];
#pragma unroll
        for (int i = 1; i < 4; ++i) {
            int gi = gids[i];
            float vv = rows[i][f];
            if (gi == g) {
                acc += vv;
            } else {
                atomicAdd(&out[(size_t)g * D + f], acc * cntinv[g]);
                g = gi;
                acc = vv;
            }
        }
        atomicAdd(&out[(size_t)g * D + f], acc * cntinv[g]);
    }
}

extern "C" void kernel_launch(void* const* d_in, const int* in_sizes, int n_in,
                              void* d_out, int out_size, void* d_ws, size_t ws_size,
                              hipStream_t stream) {
    const float* x = (const float*)d_in[0];
    const int* ei = (const int*)d_in[1];
    const int* batch = (const int*)d_in[2];
    const float* W = (const float*)d_in[3];
    const float* b = (const float*)d_in[4];
    const float* pa = (const float*)d_in[5];
    float* out = (float*)d_out;

    const int N = in_sizes[0] / D;
    const int E = in_sizes[1] / 2;
    const int* src = ei;
    const int* dst = ei + E;

    const int nb1 = (N + BUCK - 1) >> BSH;    // 128-node buckets (100k -> 782)
    const int nblk = (E + EPB - 1) / EPB;     // ascatter blocks (1.6M -> 782)
    const int mean = (E + nb1 - 1) / nb1;     // mean edges per bucket (~2047)
    const int cap = mean + mean / 5 + 384;    // fixed segment capacity (~17 sigma margin)

    char* w = (char*)d_ws;
    auto carve = [&](size_t bytes) {
        void* p = (void*)w;
        w += (bytes + 255) & ~(size_t)255;
        return p;
    };
    ushort_t* h = (ushort_t*)carve((size_t)N * D * sizeof(ushort_t));   // 25.6 MB
    ushort_t* Wp = (ushort_t*)carve((size_t)D * D * sizeof(ushort_t));
    int* deg = (int*)carve((size_t)N * sizeof(int));
    int* rs = (int*)carve((size_t)N * sizeof(int));
    int* csr = (int*)carve((size_t)nb1 * cap * sizeof(int));            // ~8.9 MB
    int* ebuf = (int*)carve((size_t)nb1 * cap * sizeof(int));           // ~8.9 MB (packed)
    int* cursor = (int*)carve(NB1MAX * sizeof(int));
    float* cntinv = (float*)carve(NG * sizeof(float));

    k_init<<<1, 256, 0, stream>>>(W, Wp, batch, N, cntinv, out, cursor, nb1, cap);
    k_ascatter<<<nblk, 256, 0, stream>>>(src, dst, E, nb1, cursor, ebuf);
    k_bucket<<<nb1, 256, 0, stream>>>(ebuf, cursor, cap, nb1, N, rs, deg, csr);
    k_gemm<<<(N + 63) / 64, 256, 0, stream>>>(x, Wp, deg, h, N);
    k_gather<<<(N + 3) / 4, 256, 0, stream>>>(h, rs, deg, csr, batch, b, pa, cntinv, out, N);
}

// Round 15
// 270.124 us; speedup vs baseline: 1.1684x; 1.1684x over previous
//
#include <hip/hip_runtime.h>

#define D 128
#define NG 128
#define EPB 8192      // edges per ascatter block
#define NB1MAX 512    // max coarse buckets (N/256); N=100k -> 391

typedef unsigned short ushort_t;
typedef __bf16 bf16x8 __attribute__((ext_vector_type(8)));
typedef float floatx4 __attribute__((ext_vector_type(4)));

static __device__ __forceinline__ unsigned short f2bf(float f) {
    unsigned u = __float_as_uint(f);
    unsigned r = (u + 0x7fffu + ((u >> 16) & 1u)) >> 16;  // RNE
    return (unsigned short)r;
}
static __device__ __forceinline__ float bflo(unsigned v) { return __uint_as_float(v << 16); }
static __device__ __forceinline__ float bfhi(unsigned v) { return __uint_as_float(v & 0xffff0000u); }

// ---------- k_init (1 block): packW + 1/graph-counts (binary search) + cursor init ----------
__global__ __launch_bounds__(256) void k_init(const float* __restrict__ W, ushort_t* __restrict__ Wp,
                                              const int* __restrict__ batch, int N,
                                              float* __restrict__ cntinv,
                                              int* __restrict__ cursor, int nb1, int cap) {
    int tid = threadIdx.x;
    for (int t = tid; t < D * D; t += 256) {
        int c = t >> 7, k = t & 127;
        Wp[t] = f2bf(W[k * D + c]);
    }
    for (int b = tid; b < nb1; b += 256) cursor[b] = b * cap;
    if (tid < NG) {
        int g = tid;
        int lo = 0, hi = N;
        while (lo < hi) { int mid = (lo + hi) >> 1; if (batch[mid] < g) lo = mid + 1; else hi = mid; }
        int a = lo;
        hi = N;
        while (lo < hi) { int mid = (lo + hi) >> 1; if (batch[mid] < g + 1) lo = mid + 1; else hi = mid; }
        int c = lo - a;
        cntinv[g] = 1.0f / (float)(c > 1 ? c : 1);
    }
}

// ---------- k_ascatter: stash dst in LDS, hist, run alloc via global cursor, scatter packed 4B ----------
__global__ __launch_bounds__(256) void k_ascatter(const int* __restrict__ src, const int* __restrict__ dst,
                                                  int E, int nb1, int* __restrict__ cursor,
                                                  int* __restrict__ ebuf) {
    __shared__ int sd[EPB];        // 32 KB (dst only)
    __shared__ int hist[NB1MAX];   // 2 KB
    __shared__ int curs[NB1MAX];   // 2 KB
    int tid = threadIdx.x;
    for (int b = tid; b < nb1; b += 256) hist[b] = 0;
    __syncthreads();
    int base = blockIdx.x * EPB;
    int cntv = E - base; if (cntv > EPB) cntv = EPB;
    for (int k = tid; k < cntv; k += 256) {
        int dv = dst[base + k];
        sd[k] = dv;
        atomicAdd(&hist[dv >> 8], 1);
    }
    __syncthreads();
    for (int b = tid; b < nb1; b += 256) {
        int v = hist[b];
        curs[b] = v ? atomicAdd(&cursor[b], v) : 0;
    }
    __syncthreads();
    for (int k = tid; k < cntv; k += 256) {
        int dv = sd[k];
        int sv = src[base + k];           // L2-hot re-read, coalesced
        int pos = atomicAdd(&curs[dv >> 8], 1);
        ebuf[pos] = sv | ((dv & 255) << 24);
    }
}

// ---------- k_bucket: per-bucket fine sort -> rs, deg, csr (LDS atomics only) ----------
__global__ __launch_bounds__(256) void k_bucket(const int* __restrict__ ebuf, const int* __restrict__ cursor,
                                                int cap, int nb1, int N,
                                                int* __restrict__ rs, int* __restrict__ deg,
                                                int* __restrict__ csr) {
    __shared__ int hist[256];
    __shared__ int sc[256];
    __shared__ int curs[256];
    int tid = threadIdx.x;
    int b = blockIdx.x;
    int s = b * cap;
    int e = cursor[b];                  // after ascatter: s + bucket edge count
    int n0 = b << 8;

    hist[tid] = 0;
    __syncthreads();
    for (int i = s + tid; i < e; i += 256) atomicAdd(&hist[(unsigned)ebuf[i] >> 24], 1);
    __syncthreads();
    int v = hist[tid];
    sc[tid] = v;
    __syncthreads();
    for (int off = 1; off < 256; off <<= 1) {
        int t = (tid >= off) ? sc[tid - off] : 0;
        __syncthreads();
        sc[tid] += t;
        __syncthreads();
    }
    int excl = sc[tid] - v;
    int node = n0 + tid;
    if (node < N) {
        rs[node] = s + excl;
        deg[node] = v;
    }
    curs[tid] = s + excl;
    __syncthreads();
    for (int i = s + tid; i < e; i += 256) {
        int p = ebuf[i];
        int pos = atomicAdd(&curs[(unsigned)p >> 24], 1);
        csr[pos] = p & 0x00FFFFFF;
    }
}

// ---------- MFMA GEMM: h[r][c] = bf16( dinv[r] * sum_k x[r][k]*W[k][c] ) ----------
__global__ __launch_bounds__(256) void k_gemm(const float* __restrict__ x, const ushort_t* __restrict__ Wp,
                                              const int* __restrict__ deg, ushort_t* __restrict__ h, int N) {
    __shared__ ushort_t hs[64][130];
    const int tid = threadIdx.x;
    const int w = tid >> 6;
    const int lane = tid & 63;
    const int q = lane >> 4;
    const int m = lane & 15;
    const int row0 = blockIdx.x * 64;
    const int arow = row0 + w * 16 + m;

    floatx4 acc[8];
#pragma unroll
    for (int nt = 0; nt < 8; ++nt) acc[nt] = (floatx4){0.f, 0.f, 0.f, 0.f};

    const bool rowok = (arow < N);
    const float* xrow = x + (size_t)arow * D;

#pragma unroll
    for (int kb = 0; kb < 4; ++kb) {
        union { bf16x8 v; ushort_t u[8]; } af;
        if (rowok) {
            float4 v0 = *(const float4*)&xrow[kb * 32 + q * 8];
            float4 v1 = *(const float4*)&xrow[kb * 32 + q * 8 + 4];
            af.u[0] = f2bf(v0.x); af.u[1] = f2bf(v0.y); af.u[2] = f2bf(v0.z); af.u[3] = f2bf(v0.w);
            af.u[4] = f2bf(v1.x); af.u[5] = f2bf(v1.y); af.u[6] = f2bf(v1.z); af.u[7] = f2bf(v1.w);
        } else {
#pragma unroll
            for (int j = 0; j < 8; ++j) af.u[j] = 0;
        }
#pragma unroll
        for (int nt = 0; nt < 8; ++nt) {
            int c = nt * 16 + m;
            const bf16x8 bf = *(const bf16x8*)(Wp + (size_t)c * D + kb * 32 + q * 8);
            acc[nt] = __builtin_amdgcn_mfma_f32_16x16x32_bf16(af.v, bf, acc[nt], 0, 0, 0);
        }
    }

    float di[4];
#pragma unroll
    for (int r = 0; r < 4; ++r) {
        int row = row0 + w * 16 + q * 4 + r;
        di[r] = (row < N) ? rsqrtf((float)(deg[row] + 1)) : 0.f;
    }
#pragma unroll
    for (int nt = 0; nt < 8; ++nt) {
        int c = nt * 16 + m;
#pragma unroll
        for (int r = 0; r < 4; ++r) {
            hs[w * 16 + q * 4 + r][c] = f2bf(acc[nt][r] * di[r]);
        }
    }
    __syncthreads();
#pragma unroll
    for (int it = 0; it < 8; ++it) {
        int f = it * 256 + tid;
        int r = f >> 5;
        int cq = f & 31;
        int row = row0 + r;
        if (row < N) {
            const ushort_t* p = &hs[r][cq * 4];
            uint2 vv;
            vv.x = (unsigned)p[0] | ((unsigned)p[1] << 16);
            vv.y = (unsigned)p[2] | ((unsigned)p[3] << 16);
            *(uint2*)&h[(size_t)row * D + cq * 4] = vv;
        }
    }
}

// ---------- gather: one wave/node, half-wave split, flush scaled by 1/cnt into out ----------
__global__ __launch_bounds__(256) void k_gather(const ushort_t* __restrict__ h, const int* __restrict__ rs,
                                                const int* __restrict__ deg, const int* __restrict__ csr,
                                                const int* __restrict__ batch, const float* __restrict__ b,
                                                const float* __restrict__ pa, const float* __restrict__ cntinv,
                                                float* __restrict__ out, int N) {
    __shared__ float rows[4][128];
    __shared__ int gids[4];
    const int wave = threadIdx.x >> 6;
    const int lane = threadIdx.x & 63;
    const int half = lane >> 5;        // half-wave: 0 -> even edges, 1 -> odd edges
    const int fl = lane & 31;          // feature lane: feats fl*4 .. fl*4+3
    const int node = blockIdx.x * 4 + wave;
    const int nodeC = (node < N) ? node : (N - 1);
    const bool valid = (node < N);

    float a0 = 0.f, a1 = 0.f, a2 = 0.f, a3 = 0.f;

    int start = rs[nodeC];
    int len = valid ? deg[nodeC] : 0;
    for (int o = 0; o < len; o += 64) {
        int m = len - o;
        if (m > 64) m = 64;
        int idx = (o + lane < len) ? csr[start + o + lane] : 0;
        int j = 0;
        for (; j + 8 <= m; j += 8) {     // 8 edges per group, 4 per half (4 loads in flight)
            int i0 = __shfl(idx, j + half);
            int i1 = __shfl(idx, j + 2 + half);
            int i2 = __shfl(idx, j + 4 + half);
            int i3 = __shfl(idx, j + 6 + half);
            uint2 v0 = *(const uint2*)&h[(size_t)i0 * D + fl * 4];
            uint2 v1 = *(const uint2*)&h[(size_t)i1 * D + fl * 4];
            uint2 v2 = *(const uint2*)&h[(size_t)i2 * D + fl * 4];
            uint2 v3 = *(const uint2*)&h[(size_t)i3 * D + fl * 4];
            a0 += bflo(v0.x); a1 += bfhi(v0.x); a2 += bflo(v0.y); a3 += bfhi(v0.y);
            a0 += bflo(v1.x); a1 += bfhi(v1.x); a2 += bflo(v1.y); a3 += bfhi(v1.y);
            a0 += bflo(v2.x); a1 += bfhi(v2.x); a2 += bflo(v2.y); a3 += bfhi(v2.y);
            a0 += bflo(v3.x); a1 += bfhi(v3.x); a2 += bflo(v3.y); a3 += bfhi(v3.y);
        }
        for (; j + 2 <= m; j += 2) {     // 2 edges, 1 per half
            int i0 = __shfl(idx, j + half);
            uint2 v0 = *(const uint2*)&h[(size_t)i0 * D + fl * 4];
            a0 += bflo(v0.x); a1 += bfhi(v0.x); a2 += bflo(v0.y); a3 += bfhi(v0.y);
        }
        if (j < m) {                     // odd tail: half 0 only (correct after combine)
            int i0 = __shfl(idx, j);
            if (half == 0) {
                uint2 v0 = *(const uint2*)&h[(size_t)i0 * D + fl * 4];
                a0 += bflo(v0.x); a1 += bfhi(v0.x); a2 += bflo(v0.y); a3 += bfhi(v0.y);
            }
        }
    }

    // combine halves -> both halves hold full neighbor sums
    a0 += __shfl_xor(a0, 32);
    a1 += __shfl_xor(a1, 32);
    a2 += __shfl_xor(a2, 32);
    a3 += __shfl_xor(a3, 32);

    // self-loop term (after combine: added exactly once per half)
    uint2 sv = *(const uint2*)&h[(size_t)nodeC * D + fl * 4];
    a0 += bflo(sv.x); a1 += bfhi(sv.x); a2 += bflo(sv.y); a3 += bfhi(sv.y);

    float dinv = rsqrtf((float)(len + 1));
    float4 bb = *(const float4*)&b[fl * 4];
    float4 aa = *(const float4*)&pa[fl * 4];
    float v0 = a0 * dinv + bb.x;
    float v1 = a1 * dinv + bb.y;
    float v2 = a2 * dinv + bb.z;
    float v3 = a3 * dinv + bb.w;
    v0 = v0 > 0.f ? v0 : aa.x * v0;
    v1 = v1 > 0.f ? v1 : aa.y * v1;
    v2 = v2 > 0.f ? v2 : aa.z * v2;
    v3 = v3 > 0.f ? v3 : aa.w * v3;
    float ss = v0 * v0 + v1 * v1 + v2 * v2 + v3 * v3;
#pragma unroll
    for (int o = 16; o > 0; o >>= 1) ss += __shfl_xor(ss, o);   // within each half-wave
    float inv = valid ? (1.0f / fmaxf(sqrtf(ss), 1e-12f)) : 0.f;

    if (half == 0) {
        *(float4*)&rows[wave][fl * 4] = make_float4(v0 * inv, v1 * inv, v2 * inv, v3 * inv);
        if (fl == 0) gids[wave] = batch[nodeC];
    }
    __syncthreads();

    // run-merge flush, scaled by 1/cnt(graph): atomics accumulate the final mean directly in out
    if (threadIdx.x < 128) {
        int f = threadIdx.x;
        float acc = rows[0][f];
        int g = gids[0];
#pragma unroll
        for (int i = 1; i < 4; ++i) {
            int gi = gids[i];
            float vv = rows[i][f];
            if (gi == g) {
                acc += vv;
            } else {
                atomicAdd(&out[(size_t)g * D + f], acc * cntinv[g]);
                g = gi;
                acc = vv;
            }
        }
        atomicAdd(&out[(size_t)g * D + f], acc * cntinv[g]);
    }
}

extern "C" void kernel_launch(void* const* d_in, const int* in_sizes, int n_in,
                              void* d_out, int out_size, void* d_ws, size_t ws_size,
                              hipStream_t stream) {
    const float* x = (const float*)d_in[0];
    const int* ei = (const int*)d_in[1];
    const int* batch = (const int*)d_in[2];
    const float* W = (const float*)d_in[3];
    const float* b = (const float*)d_in[4];
    const float* pa = (const float*)d_in[5];
    float* out = (float*)d_out;

    const int N = in_sizes[0] / D;
    const int E = in_sizes[1] / 2;
    const int* src = ei;
    const int* dst = ei + E;

    const int nb1 = (N + 255) >> 8;           // coarse buckets (256 nodes)
    const int nblk = (E + EPB - 1) / EPB;     // ascatter blocks
    const int mean = (E + nb1 - 1) / nb1;     // mean edges per bucket
    const int cap = mean + mean / 5 + 512;    // fixed segment capacity (>>8 sigma for uniform dst)

    char* w = (char*)d_ws;
    auto carve = [&](size_t bytes) {
        void* p = (void*)w;
        w += (bytes + 255) & ~(size_t)255;
        return p;
    };
    ushort_t* h = (ushort_t*)carve((size_t)N * D * sizeof(ushort_t));   // 25.6 MB
    ushort_t* Wp = (ushort_t*)carve((size_t)D * D * sizeof(ushort_t));
    int* deg = (int*)carve((size_t)N * sizeof(int));
    int* rs = (int*)carve((size_t)N * sizeof(int));
    int* csr = (int*)carve((size_t)nb1 * cap * sizeof(int));            // ~8.5 MB
    int* ebuf = (int*)carve((size_t)nb1 * cap * sizeof(int));           // ~8.5 MB (packed)
    int* cursor = (int*)carve(NB1MAX * sizeof(int));
    float* cntinv = (float*)carve(NG * sizeof(float));

    hipMemsetAsync(out, 0, (size_t)NG * D * sizeof(float), stream);     // gather accumulates into out

    k_init<<<1, 256, 0, stream>>>(W, Wp, batch, N, cntinv, cursor, nb1, cap);
    k_ascatter<<<nblk, 256, 0, stream>>>(src, dst, E, nb1, cursor, ebuf);
    k_bucket<<<nb1, 256, 0, stream>>>(ebuf, cursor, cap, nb1, N, rs, deg, csr);
    k_gemm<<<(N + 63) / 64, 256, 0, stream>>>(x, Wp, deg, h, N);
    k_gather<<<(N + 3) / 4, 256, 0, stream>>>(h, rs, deg, csr, batch, b, pa, cntinv, out, N);
}